// Round 1
// baseline (898.557 us; speedup 1.0000x reference)
//
#include <hip/hip_runtime.h>

// KV cache roll-and-append:
//   out_k[b,h,l,:] = k_cache[b,h,l+1,:]  (l < 4095)
//   out_k[b,h,4095,:] = k[b,h,0,:]
// same for v. Shapes: B=4,H=32,L=4096,D=128, fp32. Out = [k_out ; v_out] packed.
// Pure streaming copy: ~1.07 GB HBM traffic, floor ~170 us @ 6.3 TB/s.
//
// This version vs previous (811.9 us):
//  - grid-stride persistent-style blocks: 2048x2 blocks * 256 thr (32 waves/CU)
//    instead of 65536x2 one-shot (16 B/thread).
//  - 4-deep unroll, loads batched before stores -> 4 VMEM loads in flight/thread.
//  - nontemporal load/store: 1 GiB stream-once traffic should not allocate in
//    L2/L3 (working set is 4x the 256 MiB L3 -> pure pollution otherwise).

typedef float f32x4 __attribute__((ext_vector_type(4)));

constexpr long long N_PER_OUT = 4LL * 32 * 4096 * 128;   // 67,108,864 floats/tensor
constexpr long long NVEC     = N_PER_OUT >> 2;           // 16,777,216 float4/tensor
constexpr int BLOCK  = 256;
constexpr int GRIDX  = 2048;
constexpr int UNROLL = 4;

// float4-unit geometry: row (one (b,h,l,:) slice) = 32 float4; 4096 rows per (b,h).
//   l   = (i >> 5) & 4095
//   bh  = i >> 17
//   d4  = i & 31

__global__ __launch_bounds__(BLOCK)
void kv_roll_kernel(const f32x4* __restrict__ k_cache,
                    const f32x4* __restrict__ k_new,
                    const f32x4* __restrict__ v_cache,
                    const f32x4* __restrict__ v_new,
                    f32x4* __restrict__ out) {
    const f32x4* __restrict__ cache = blockIdx.y ? v_cache : k_cache;
    const f32x4* __restrict__ ntok  = blockIdx.y ? v_new   : k_new;
    f32x4* __restrict__ o = out + (long long)blockIdx.y * NVEC;

    const long long T    = (long long)GRIDX * BLOCK;       // threads per plane
    const long long base = (long long)blockIdx.x * BLOCK + threadIdx.x;

    for (long long i0 = base; i0 < NVEC; i0 += T * UNROLL) {
        f32x4 val[UNROLL];
#pragma unroll
        for (int j = 0; j < UNROLL; ++j) {
            const long long i = i0 + (long long)j * T;
            if (((i >> 5) & 4095) != 4095) {
                // shifted copy: src row = out row + 1  => +32 float4
                val[j] = __builtin_nontemporal_load(&cache[i + 32]);
            } else {
                // last row of each (b,h): take the new token
                val[j] = ntok[((i >> 17) << 5) | (i & 31)];
            }
        }
#pragma unroll
        for (int j = 0; j < UNROLL; ++j) {
            const long long i = i0 + (long long)j * T;
            __builtin_nontemporal_store(val[j], &o[i]);
        }
    }
}

extern "C" void kernel_launch(void* const* d_in, const int* in_sizes, int n_in,
                              void* d_out, int out_size, void* d_ws, size_t ws_size,
                              hipStream_t stream) {
    const f32x4* k_cache = (const f32x4*)d_in[0];
    const f32x4* v_cache = (const f32x4*)d_in[1];
    const f32x4* k_new   = (const f32x4*)d_in[2];
    const f32x4* v_new   = (const f32x4*)d_in[3];
    // d_in[4] = context_length (== L=4096, full roll) -- baked into index math.
    f32x4* out = (f32x4*)d_out;

    dim3 grid(GRIDX, 2, 1);
    kv_roll_kernel<<<grid, BLOCK, 0, stream>>>(k_cache, k_new, v_cache, v_new, out);
}